// Round 1
// baseline (12728.759 us; speedup 1.0000x reference)
//
#include <hip/hip_runtime.h>
#include <math.h>

#define BSZ 32
#define TT  32
#define XD  128
#define HD  512
#define VT  2048
#define WD  64
#define RDM 4
#define NDM 1024
#define ET  463
#define GKS 8
#define VKS 16

__device__ __forceinline__ float sigf(float x){ return 1.f/(1.f+expf(-x)); }
__device__ __forceinline__ float logsigf(float x){
    return (x >= 0.f) ? -log1pf(expf(-x)) : x - log1pf(expf(x));
}

// ---- 1024-thread block reductions (2-level: wave64 shfl + 16 partials) -------------
__device__ __forceinline__ float bsum(float v, float* red, int tid){
    #pragma unroll
    for (int off = 32; off > 0; off >>= 1) v += __shfl_xor(v, off);
    if ((tid & 63) == 0) red[tid >> 6] = v;
    __syncthreads();
    if (tid == 0){
        float s = red[0];
        #pragma unroll
        for (int i = 1; i < 16; ++i) s += red[i];
        red[16] = s;
    }
    __syncthreads();
    float r = red[16];
    __syncthreads();
    return r;
}
__device__ __forceinline__ float bmax(float v, float* red, int tid){
    #pragma unroll
    for (int off = 32; off > 0; off >>= 1) v = fmaxf(v, __shfl_xor(v, off));
    if ((tid & 63) == 0) red[tid >> 6] = v;
    __syncthreads();
    if (tid == 0){
        float s = red[0];
        #pragma unroll
        for (int i = 1; i < 16; ++i) s = fmaxf(s, red[i]);
        red[16] = s;
    }
    __syncthreads();
    float r = red[16];
    __syncthreads();
    return r;
}

// ---------------- batchnorm of x for ALL timesteps (recurrence-independent) ---------
__global__ void dnc_bnx(const float* __restrict__ x, float* __restrict__ bnx){
    int t = blockIdx.x, k = threadIdx.x;   // 128 threads
    float vals[BSZ];
    float s = 0.f;
    #pragma unroll
    for (int b = 0; b < BSZ; ++b){ vals[b] = x[(b*TT + t)*XD + k]; s += vals[b]; }
    float mean = s * (1.f/BSZ);
    float ss = 0.f;
    #pragma unroll
    for (int b = 0; b < BSZ; ++b){ float d = vals[b]-mean; ss += d*d; }
    float inv = 1.f / sqrtf(ss*(1.f/BSZ) + 1e-5f);
    #pragma unroll
    for (int b = 0; b < BSZ; ++b) bnx[((size_t)t*BSZ + b)*XD + k] = (vals[b]-mean)*inv;
}

// ---------------- LSTM pre-activation GEMM, 3-source (A | B | h), k-split -----------
// grid (16 jchunks, 2 dirs, GKS), block 256. thread: 4 j x 4 b accumulators.
__global__ void dnc_lstm_gemm(const float* __restrict__ srcA, int KA,
                              const float* __restrict__ srcB, int KB,
                              const float* __restrict__ hbase,
                              const float* __restrict__ Wih, const float* __restrict__ Whh,
                              float* __restrict__ gpart){
    const int jc = blockIdx.x, d = blockIdx.y, ks = blockIdx.z;
    const int tid = threadIdx.x;
    const int jg = tid & 31, bg = tid >> 5;
    const int j0 = jc*128 + jg*4;
    const int b0 = bg*4;
    const int K1 = KA + KB;
    const int cA = KA >> 6;
    const int cin = K1 >> 6;
    const int nct = cin + 8;               // + HD/64 h-chunks
    const int per = (nct + GKS - 1) / GKS;
    int c0 = ks*per; int c1 = min(nct, c0+per);
    __shared__ __align__(16) float tile[64*36];
    float acc[4][4] = {{0}};
    for (int c = c0; c < c1; ++c){
        const float* src; int stride, kb, wcol; const float* Wb; int Kw;
        if (c < cA){ src = srcA; stride = KA; kb = c*64; wcol = c*64;
                     Wb = Wih + (size_t)d*2048*K1; Kw = K1; }
        else if (c < cin){ src = srcB; stride = KB; kb = (c-cA)*64; wcol = c*64;
                           Wb = Wih + (size_t)d*2048*K1; Kw = K1; }
        else { src = hbase + d*(BSZ*HD); stride = HD; kb = (c-cin)*64; wcol = kb;
               Wb = Whh + (size_t)d*2048*512; Kw = 512; }
        #pragma unroll
        for (int i = 0; i < 8; ++i){
            int idx = i*256 + tid; int kk = idx & 63, b = idx >> 6;
            tile[kk*36 + b] = src[b*stride + kb + kk];
        }
        __syncthreads();
        const float* w0p = Wb + (size_t)(j0+0)*Kw + wcol;
        const float* w1p = Wb + (size_t)(j0+1)*Kw + wcol;
        const float* w2p = Wb + (size_t)(j0+2)*Kw + wcol;
        const float* w3p = Wb + (size_t)(j0+3)*Kw + wcol;
        #pragma unroll
        for (int kk = 0; kk < 64; kk += 4){
            float4 a0 = *(const float4*)&tile[(kk+0)*36 + b0];
            float4 a1 = *(const float4*)&tile[(kk+1)*36 + b0];
            float4 a2 = *(const float4*)&tile[(kk+2)*36 + b0];
            float4 a3 = *(const float4*)&tile[(kk+3)*36 + b0];
            float4 w;
            #define ACCJ(JJ, WP) \
                w = *(const float4*)(WP + kk); \
                acc[JJ][0] += a0.x*w.x + a1.x*w.y + a2.x*w.z + a3.x*w.w; \
                acc[JJ][1] += a0.y*w.x + a1.y*w.y + a2.y*w.z + a3.y*w.w; \
                acc[JJ][2] += a0.z*w.x + a1.z*w.y + a2.z*w.z + a3.z*w.w; \
                acc[JJ][3] += a0.w*w.x + a1.w*w.y + a2.w*w.z + a3.w*w.w;
            ACCJ(0, w0p) ACCJ(1, w1p) ACCJ(2, w2p) ACCJ(3, w3p)
            #undef ACCJ
        }
        __syncthreads();
    }
    #pragma unroll
    for (int jj = 0; jj < 4; ++jj){
        #pragma unroll
        for (int bb = 0; bb < 4; ++bb)
            gpart[((size_t)(d*GKS + ks)*BSZ + (b0+bb))*2048 + (j0+jj)] = acc[jj][bb];
    }
}

// ---------------- LSTM gates -> h, c (also writes flat, optional next-layer input) ---
__global__ void dnc_gates(const float* __restrict__ gpart,
                          const float* __restrict__ bih, const float* __restrict__ bhh,
                          float* __restrict__ cstate, float* __restrict__ hstate,
                          float* __restrict__ flat, float* __restrict__ lout, int l){
    int idx = blockIdx.x*256 + threadIdx.x;
    int u = idx & 511, b = (idx >> 9) & 31, d = idx >> 14;
    int cell = 2*l + d;
    float g[4];
    #pragma unroll
    for (int xg = 0; xg < 4; ++xg){
        int j = xg*512 + u;
        float s = bih[d*2048 + j] + bhh[d*2048 + j];
        #pragma unroll
        for (int ks = 0; ks < GKS; ++ks)
            s += gpart[((size_t)(d*GKS + ks)*BSZ + b)*2048 + j];
        g[xg] = s;
    }
    float ig = sigf(g[0]), fg = sigf(g[1]), og = sigf(g[3]);
    float gg = tanhf(g[2]);
    int ci = (cell*BSZ + b)*HD + u;
    float c2 = fg*cstate[ci] + ig*gg;
    cstate[ci] = c2;
    float h = og*tanhf(c2);
    hstate[ci] = h;
    flat[b*2048 + cell*HD + u] = h;
    if (lout) lout[b*1024 + d*HD + u] = h;
}

// ---------------- combined GEMV: flat@Wy (blocks 0-15) + flat@WE (blocks 16-19) ------
__global__ void dnc_gemv2(const float* __restrict__ fin, const float* __restrict__ Wy,
                          const float* __restrict__ WE,
                          float* __restrict__ vtp, float* __restrict__ ep){
    const int bx = blockIdx.x, ksi = blockIdx.y;
    const float* Wm; float* outp; int Mdim, mb;
    if (bx < 16){ Wm = Wy; outp = vtp; Mdim = VT; mb = bx; }
    else        { Wm = WE; outp = ep;  Mdim = ET; mb = bx - 16; }
    const int tid = threadIdx.x;
    const int lane = tid & 63, bg = tid >> 6;
    const int b0 = bg*8;
    const int m0 = mb*128 + lane, m1 = m0 + 64;
    const int k0 = ksi*128;
    __shared__ __align__(16) float tile[128*36];
    #pragma unroll
    for (int i = 0; i < 16; ++i){
        int idx = i*256 + tid; int kk = idx & 127, b = idx >> 7;
        tile[kk*36 + b] = fin[b*2048 + k0 + kk];
    }
    __syncthreads();
    bool v0 = m0 < Mdim, v1 = m1 < Mdim;
    float acc[16] = {0};
    for (int kk = 0; kk < 128; ++kk){
        float4 pq = *(const float4*)&tile[kk*36 + b0];
        float4 qq = *(const float4*)&tile[kk*36 + b0 + 4];
        const float* wr = Wm + (size_t)(k0+kk)*Mdim;
        float w0 = v0 ? wr[m0] : 0.f;
        float w1 = v1 ? wr[m1] : 0.f;
        acc[0]+=pq.x*w0; acc[1]+=pq.y*w0; acc[2]+=pq.z*w0; acc[3]+=pq.w*w0;
        acc[4]+=qq.x*w0; acc[5]+=qq.y*w0; acc[6]+=qq.z*w0; acc[7]+=qq.w*w0;
        acc[8]+=pq.x*w1; acc[9]+=pq.y*w1; acc[10]+=pq.z*w1; acc[11]+=pq.w*w1;
        acc[12]+=qq.x*w1; acc[13]+=qq.y*w1; acc[14]+=qq.z*w1; acc[15]+=qq.w*w1;
    }
    if (v0){
        #pragma unroll
        for (int bb = 0; bb < 8; ++bb)
            outp[((size_t)ksi*BSZ + b0+bb)*Mdim + m0] = acc[bb];
    }
    if (v1){
        #pragma unroll
        for (int bb = 0; bb < 8; ++bb)
            outp[((size_t)ksi*BSZ + b0+bb)*Mdim + m1] = acc[8+bb];
    }
}

// ---------------- MEGA memory-subsystem kernel: one block per batch element ----------
// ln -> usage -> bitonic argsort -> cumprod alloc -> cw score+softmax+ww ->
// memory update (+row norm) -> read scores+softmax -> read vectors
__global__ __launch_bounds__(1024) void dnc_mega(
    const float* __restrict__ ep, float* __restrict__ M,
    float* __restrict__ ubuf, float* __restrict__ lww,
    float* __restrict__ lrw, float* __restrict__ lrv)
{
    const int b = blockIdx.x, tid = threadIdx.x;
    __shared__ float red[32];
    __shared__ float ivS[ET+1];
    __shared__ unsigned long long keysS[1024];
    __shared__ float paS[1024], pbS[1024];
    __shared__ float allocS[1024];
    __shared__ float keyS[64], eraseS[64], wvecS[64];
    __shared__ float rknS[256], nrmS[4];
    __shared__ float rwS[4*1024];
    __shared__ float rvS[1024];

    // ---- layernorm of WE-gemv partial sums -> iv (LDS only) ----
    float myv = 0.f;
    if (tid < ET){
        float v = 0.f;
        #pragma unroll
        for (int s = 0; s < VKS; ++s) v += ep[((size_t)s*BSZ + b)*ET + tid];
        myv = v;
    }
    float mean = bsum((tid < ET) ? myv : 0.f, red, tid) * (1.f/ET);
    float dd = (tid < ET) ? (myv - mean) : 0.f;
    float var = bsum(dd*dd, red, tid) * (1.f/ET);
    float rinv = 1.f / sqrtf(var + 1e-5f);
    if (tid < ET) ivS[tid] = (myv - mean)*rinv;
    __syncthreads();

    // ---- usage ----
    const int n = tid;
    float4 lw4 = *(const float4*)&lrw[((size_t)b*1024 + n)*4];
    float f0 = sigf(ivS[453]), f1 = sigf(ivS[454]), f2 = sigf(ivS[455]), f3 = sigf(ivS[456]);
    float ret = (1.f-f0*lw4.x)*(1.f-f1*lw4.y)*(1.f-f2*lw4.z)*(1.f-f3*lw4.w);
    float uo = ubuf[b*1024+n], lwo = lww[b*1024+n];
    float un = (uo + lwo - uo*lwo)*ret;
    ubuf[b*1024+n] = un;

    // ---- stable bitonic argsort on (u bits, idx) ----
    keysS[tid] = ((unsigned long long)__float_as_uint(un) << 32) | (unsigned)tid;
    __syncthreads();
    for (int k = 2; k <= 1024; k <<= 1){
        for (int j = k >> 1; j > 0; j >>= 1){
            int ixj = tid ^ j;
            if (ixj > tid){
                unsigned long long a = keysS[tid], c = keysS[ixj];
                bool up = ((tid & k) == 0);
                if ((a > c) == up){ keysS[tid] = c; keysS[ixj] = a; }
            }
            __syncthreads();
        }
    }
    unsigned long long kv = keysS[tid];
    float su = __uint_as_float((unsigned)(kv >> 32));
    int idxv = (int)(kv & 0xffffffffu);

    // ---- inclusive cumprod scan of sorted u; alloc scatter ----
    paS[tid] = su;
    __syncthreads();
    float* sp = paS; float* dp = pbS;
    for (int off = 1; off < 1024; off <<= 1){
        float v = sp[tid];
        if (tid >= off) v *= sp[tid - off];
        dp[tid] = v;
        __syncthreads();
        float* t2 = sp; sp = dp; dp = t2;
    }
    float cp = (tid == 0) ? 1.f : sp[tid-1];
    allocS[idxv] = (1.f - su)*cp;

    // ---- stage write key / erase / wvec / normalized read keys ----
    if (tid < 64){
        keyS[tid]   = ivS[260+tid];
        eraseS[tid] = sigf(ivS[325+tid]);
        wvecS[tid]  = ivS[389+tid];
    }
    if (tid < 4){
        float s = 0.f;
        #pragma unroll
        for (int w = 0; w < 64; ++w){ float v = ivS[w*4 + tid]; s += v*v; }
        nrmS[tid] = sqrtf(s) + 1e-8f;
    }
    __syncthreads();
    if (tid < 256) rknS[tid] = ivS[tid] / nrmS[tid & 3];
    __syncthreads();   // covers allocS scatter + rknS

    // ---- content-write score on OLD M ----
    float ksq = 0.f;
    #pragma unroll
    for (int w = 0; w < 64; ++w) ksq += keyS[w]*keyS[w];
    float kden = sqrtf(ksq) + 1e-8f;
    float wb = 1.f - logsigf(ivS[324]);
    float* Mrow = M + ((size_t)b*1024 + n)*64;
    float dot = 0.f, msq = 0.f;
    #pragma unroll
    for (int w = 0; w < 64; w += 4){
        float4 mv = *(const float4*)(Mrow + w);
        dot += mv.x*keyS[w] + mv.y*keyS[w+1] + mv.z*keyS[w+2] + mv.w*keyS[w+3];
        msq += mv.x*mv.x + mv.y*mv.y + mv.z*mv.z + mv.w*mv.w;
    }
    float sc = wb*dot/((sqrtf(msq) + 1e-8f)*kden);
    float mxc = bmax(sc, red, tid);
    float ec = expf(sc - mxc);
    float totc = bsum(ec, red, tid);
    float cwv = ec/totc;
    float ag = sigf(ivS[457]), wg = sigf(ivS[458]);
    float wwv = wg*(ag*allocS[n] + (1.f-ag)*cwv);
    lww[b*1024+n] = wwv;

    // ---- memory update + row norm + read scores (fused, per own row) ----
    float rb0 = 1.f - logsigf(ivS[256]);
    float rb1 = 1.f - logsigf(ivS[257]);
    float rb2 = 1.f - logsigf(ivS[258]);
    float rb3 = 1.f - logsigf(ivS[259]);
    float dr0=0.f, dr1=0.f, dr2=0.f, dr3=0.f, msq2=0.f;
    #pragma unroll
    for (int w = 0; w < 64; w += 4){
        float4 mv = *(const float4*)(Mrow + w);
        mv.x = mv.x*(1.f - wwv*eraseS[w+0]) + wwv*wvecS[w+0];
        mv.y = mv.y*(1.f - wwv*eraseS[w+1]) + wwv*wvecS[w+1];
        mv.z = mv.z*(1.f - wwv*eraseS[w+2]) + wwv*wvecS[w+2];
        mv.w = mv.w*(1.f - wwv*eraseS[w+3]) + wwv*wvecS[w+3];
        *(float4*)(Mrow + w) = mv;
        msq2 += mv.x*mv.x + mv.y*mv.y + mv.z*mv.z + mv.w*mv.w;
        dr0 += mv.x*rknS[(w+0)*4+0] + mv.y*rknS[(w+1)*4+0] + mv.z*rknS[(w+2)*4+0] + mv.w*rknS[(w+3)*4+0];
        dr1 += mv.x*rknS[(w+0)*4+1] + mv.y*rknS[(w+1)*4+1] + mv.z*rknS[(w+2)*4+1] + mv.w*rknS[(w+3)*4+1];
        dr2 += mv.x*rknS[(w+0)*4+2] + mv.y*rknS[(w+1)*4+2] + mv.z*rknS[(w+2)*4+2] + mv.w*rknS[(w+3)*4+2];
        dr3 += mv.x*rknS[(w+0)*4+3] + mv.y*rknS[(w+1)*4+3] + mv.z*rknS[(w+2)*4+3] + mv.w*rknS[(w+3)*4+3];
    }
    float den = sqrtf(msq2) + 1e-8f;
    float v4[4] = { rb0*dr0/den, rb1*dr1/den, rb2*dr2/den, rb3*dr3/den };

    // ---- read softmax over n, per r ----
    #pragma unroll
    for (int r = 0; r < 4; ++r){
        float mr = bmax(v4[r], red, tid);
        float er = expf(v4[r] - mr);
        float tr = bsum(er, red, tid);
        float rwv = er/tr;
        rwS[r*1024 + n] = rwv;
        lrw[((size_t)b*1024 + n)*4 + r] = rwv;
    }
    __syncthreads();   // rwS + M writes visible to whole block

    // ---- read vectors: rv[w][r] = sum_n M[n][w]*rw[n][r] (n-quartered) ----
    {
        int w = tid & 63, rq = tid >> 6, rr = rq & 3, q = rq >> 2;
        const float* Mb = M + (size_t)b*65536;
        float acc = 0.f;
        for (int i = 0; i < 256; ++i){
            int nn = q*256 + i;
            acc += Mb[(size_t)nn*64 + w] * rwS[rr*1024 + nn];
        }
        rvS[tid] = acc;
    }
    __syncthreads();
    if (tid < 256){
        int w2 = tid >> 2, r2 = tid & 3;
        float s = 0.f;
        #pragma unroll
        for (int q = 0; q < 4; ++q) s += rvS[(q*4 + r2)*64 + w2];
        lrv[b*256 + tid] = s;   // layout [b][w*4+r]
    }
}

// ---------------- final: yt = rv@Wr + sum(vtp partials); out = max over t ------------
// grid 16 blocks x 256 threads; each block 128 m-cols x all 32 b; thread 4b x 4m.
__global__ void dnc_yfin(const float* __restrict__ lrv, const float* __restrict__ Wr,
                         const float* __restrict__ vtp, float* __restrict__ out, int t){
    const int tid = threadIdx.x;
    const int mg = tid & 31, bg = tid >> 5;
    const int m0 = blockIdx.x*128 + mg*4;
    const int b0 = bg*4;
    __shared__ __align__(16) float lt[256*36];   // lrv transposed [k][b], pad 36
    #pragma unroll
    for (int i = 0; i < 32; ++i){
        int idx = i*256 + tid; int k = idx & 255, b = idx >> 8;
        lt[k*36 + b] = lrv[b*256 + k];
    }
    __syncthreads();
    float acc[4][4] = {{0}};
    for (int kk = 0; kk < 256; ++kk){
        float4 av = *(const float4*)&lt[kk*36 + b0];
        float4 wv = *(const float4*)&Wr[(size_t)kk*VT + m0];
        acc[0][0]+=av.x*wv.x; acc[0][1]+=av.x*wv.y; acc[0][2]+=av.x*wv.z; acc[0][3]+=av.x*wv.w;
        acc[1][0]+=av.y*wv.x; acc[1][1]+=av.y*wv.y; acc[1][2]+=av.y*wv.z; acc[1][3]+=av.y*wv.w;
        acc[2][0]+=av.z*wv.x; acc[2][1]+=av.z*wv.y; acc[2][2]+=av.z*wv.z; acc[2][3]+=av.z*wv.w;
        acc[3][0]+=av.w*wv.x; acc[3][1]+=av.w*wv.y; acc[3][2]+=av.w*wv.z; acc[3][3]+=av.w*wv.w;
    }
    #pragma unroll
    for (int bi = 0; bi < 4; ++bi){
        int b = b0 + bi;
        float4 s = make_float4(acc[bi][0], acc[bi][1], acc[bi][2], acc[bi][3]);
        #pragma unroll
        for (int sp = 0; sp < VKS; ++sp){
            float4 vp = *(const float4*)&vtp[((size_t)sp*BSZ + b)*VT + m0];
            s.x += vp.x; s.y += vp.y; s.z += vp.z; s.w += vp.w;
        }
        float4* op = (float4*)&out[(size_t)b*VT + m0];
        if (t == 0){ *op = s; }
        else {
            float4 cur = *op;
            cur.x = fmaxf(cur.x, s.x); cur.y = fmaxf(cur.y, s.y);
            cur.z = fmaxf(cur.z, s.z); cur.w = fmaxf(cur.w, s.w);
            *op = cur;
        }
    }
}

extern "C" void kernel_launch(void* const* d_in, const int* in_sizes, int n_in,
                              void* d_out, int out_size, void* d_ws, size_t ws_size,
                              hipStream_t stream){
    const float* x      = (const float*)d_in[0];
    const float* mem0   = (const float*)d_in[1];
    const float* Wy     = (const float*)d_in[2];
    const float* WE     = (const float*)d_in[3];
    const float* Wr     = (const float*)d_in[4];
    const float* Wih0   = (const float*)d_in[5];
    const float* Whh0   = (const float*)d_in[6];
    const float* bih0   = (const float*)d_in[7];
    const float* bhh0   = (const float*)d_in[8];
    const float* Wih1   = (const float*)d_in[9];
    const float* Whh1   = (const float*)d_in[10];
    const float* bih1   = (const float*)d_in[11];
    const float* bhh1   = (const float*)d_in[12];
    float* out = (float*)d_out;

    float* p = (float*)d_ws;
    float* M      = p; p += (size_t)32*1024*64;
    float* hstate = p; p += 4*32*512;     // zero block start
    float* cstate = p; p += 4*32*512;
    float* ubuf   = p; p += 32*1024;
    float* lww    = p; p += 32*1024;
    float* lrw    = p; p += 32*1024*4;
    float* lrv    = p; p += 32*256;       // zero block end
    float* bnx    = p; p += (size_t)TT*32*128;
    float* lin1   = p; p += 32*1024;
    float* gpart  = p; p += (size_t)2*GKS*32*2048;
    float* flat   = p; p += 32*2048;
    float* vtp    = p; p += (size_t)VKS*32*2048;
    float* ep     = p; p += (size_t)VKS*32*ET;

    (void)hipMemcpyAsync(M, mem0, (size_t)32*1024*64*sizeof(float), hipMemcpyDeviceToDevice, stream);
    size_t zfloats = (size_t)(4*32*512)*2 + 32*1024*2 + 32*1024*4 + 32*256;
    (void)hipMemsetAsync(hstate, 0, zfloats*sizeof(float), stream);

    dnc_bnx<<<TT, 128, 0, stream>>>(x, bnx);

    for (int t = 0; t < TT; ++t){
        dnc_lstm_gemm<<<dim3(16,2,GKS), 256, 0, stream>>>(bnx + (size_t)t*32*128, 128,
                                                          lrv, 256, hstate, Wih0, Whh0, gpart);
        dnc_gates<<<128, 256, 0, stream>>>(gpart, bih0, bhh0, cstate, hstate, flat, lin1, 0);
        dnc_lstm_gemm<<<dim3(16,2,GKS), 256, 0, stream>>>(lin1, 1024, nullptr, 0,
                                                          hstate + 2*32*512, Wih1, Whh1, gpart);
        dnc_gates<<<128, 256, 0, stream>>>(gpart, bih1, bhh1, cstate, hstate, flat, nullptr, 1);
        dnc_gemv2<<<dim3(20,VKS), 256, 0, stream>>>(flat, Wy, WE, vtp, ep);
        dnc_mega<<<32, 1024, 0, stream>>>(ep, M, ubuf, lww, lrw, lrv);
        dnc_yfin<<<16, 256, 0, stream>>>(lrv, Wr, vtp, out, t);
    }
}

// Round 2
// 9692.589 us; speedup vs baseline: 1.3132x; 1.3132x over previous
//
#include <hip/hip_runtime.h>
#include <math.h>

#define BSZ 32
#define TT  32
#define XD  128
#define HD  512
#define VT  2048
#define WD  64
#define RDM 4
#define NDM 1024
#define ET  463
#define GKS 8
#define VKS 16

__device__ __forceinline__ float sigf(float x){ return 1.f/(1.f+expf(-x)); }
__device__ __forceinline__ float logsigf(float x){
    return (x >= 0.f) ? -log1pf(expf(-x)) : x - log1pf(expf(x));
}

// ---- 1024-thread block reductions (2-level: wave64 shfl + 16 partials) -------------
__device__ __forceinline__ float bsum(float v, float* red, int tid){
    #pragma unroll
    for (int off = 32; off > 0; off >>= 1) v += __shfl_xor(v, off);
    if ((tid & 63) == 0) red[tid >> 6] = v;
    __syncthreads();
    if (tid == 0){
        float s = red[0];
        #pragma unroll
        for (int i = 1; i < 16; ++i) s += red[i];
        red[16] = s;
    }
    __syncthreads();
    float r = red[16];
    __syncthreads();
    return r;
}
// ---- 256-thread block reductions (4 waves) -----------------------------------------
__device__ __forceinline__ float bsum256(float v, float* red, int tid){
    #pragma unroll
    for (int off = 32; off > 0; off >>= 1) v += __shfl_xor(v, off);
    if ((tid & 63) == 0) red[tid >> 6] = v;
    __syncthreads();
    float r = red[0] + red[1] + red[2] + red[3];
    __syncthreads();
    return r;
}
__device__ __forceinline__ float bmax256(float v, float* red, int tid){
    #pragma unroll
    for (int off = 32; off > 0; off >>= 1) v = fmaxf(v, __shfl_xor(v, off));
    if ((tid & 63) == 0) red[tid >> 6] = v;
    __syncthreads();
    float r = fmaxf(fmaxf(red[0], red[1]), fmaxf(red[2], red[3]));
    __syncthreads();
    return r;
}

// ---------------- batchnorm of x for ALL timesteps (recurrence-independent) ---------
__global__ void dnc_bnx(const float* __restrict__ x, float* __restrict__ bnx){
    int t = blockIdx.x, k = threadIdx.x;   // 128 threads
    float vals[BSZ];
    float s = 0.f;
    #pragma unroll
    for (int b = 0; b < BSZ; ++b){ vals[b] = x[(b*TT + t)*XD + k]; s += vals[b]; }
    float mean = s * (1.f/BSZ);
    float ss = 0.f;
    #pragma unroll
    for (int b = 0; b < BSZ; ++b){ float d = vals[b]-mean; ss += d*d; }
    float inv = 1.f / sqrtf(ss*(1.f/BSZ) + 1e-5f);
    #pragma unroll
    for (int b = 0; b < BSZ; ++b) bnx[((size_t)t*BSZ + b)*XD + k] = (vals[b]-mean)*inv;
}

// ---------------- LSTM pre-activation GEMM, 3-source (A | B | h), k-split -----------
__global__ void dnc_lstm_gemm(const float* __restrict__ srcA, int KA,
                              const float* __restrict__ srcB, int KB,
                              const float* __restrict__ hbase,
                              const float* __restrict__ Wih, const float* __restrict__ Whh,
                              float* __restrict__ gpart){
    const int jc = blockIdx.x, d = blockIdx.y, ks = blockIdx.z;
    const int tid = threadIdx.x;
    const int jg = tid & 31, bg = tid >> 5;
    const int j0 = jc*128 + jg*4;
    const int b0 = bg*4;
    const int K1 = KA + KB;
    const int cA = KA >> 6;
    const int cin = K1 >> 6;
    const int nct = cin + 8;               // + HD/64 h-chunks
    const int per = (nct + GKS - 1) / GKS;
    int c0 = ks*per; int c1 = min(nct, c0+per);
    __shared__ __align__(16) float tile[64*36];
    float acc[4][4] = {{0}};
    for (int c = c0; c < c1; ++c){
        const float* src; int stride, kb, wcol; const float* Wb; int Kw;
        if (c < cA){ src = srcA; stride = KA; kb = c*64; wcol = c*64;
                     Wb = Wih + (size_t)d*2048*K1; Kw = K1; }
        else if (c < cin){ src = srcB; stride = KB; kb = (c-cA)*64; wcol = c*64;
                           Wb = Wih + (size_t)d*2048*K1; Kw = K1; }
        else { src = hbase + d*(BSZ*HD); stride = HD; kb = (c-cin)*64; wcol = kb;
               Wb = Whh + (size_t)d*2048*512; Kw = 512; }
        #pragma unroll
        for (int i = 0; i < 8; ++i){
            int idx = i*256 + tid; int kk = idx & 63, b = idx >> 6;
            tile[kk*36 + b] = src[b*stride + kb + kk];
        }
        __syncthreads();
        const float* w0p = Wb + (size_t)(j0+0)*Kw + wcol;
        const float* w1p = Wb + (size_t)(j0+1)*Kw + wcol;
        const float* w2p = Wb + (size_t)(j0+2)*Kw + wcol;
        const float* w3p = Wb + (size_t)(j0+3)*Kw + wcol;
        #pragma unroll
        for (int kk = 0; kk < 64; kk += 4){
            float4 a0 = *(const float4*)&tile[(kk+0)*36 + b0];
            float4 a1 = *(const float4*)&tile[(kk+1)*36 + b0];
            float4 a2 = *(const float4*)&tile[(kk+2)*36 + b0];
            float4 a3 = *(const float4*)&tile[(kk+3)*36 + b0];
            float4 w;
            #define ACCJ(JJ, WP) \
                w = *(const float4*)(WP + kk); \
                acc[JJ][0] += a0.x*w.x + a1.x*w.y + a2.x*w.z + a3.x*w.w; \
                acc[JJ][1] += a0.y*w.x + a1.y*w.y + a2.y*w.z + a3.y*w.w; \
                acc[JJ][2] += a0.z*w.x + a1.z*w.y + a2.z*w.z + a3.z*w.w; \
                acc[JJ][3] += a0.w*w.x + a1.w*w.y + a2.w*w.z + a3.w*w.w;
            ACCJ(0, w0p) ACCJ(1, w1p) ACCJ(2, w2p) ACCJ(3, w3p)
            #undef ACCJ
        }
        __syncthreads();
    }
    #pragma unroll
    for (int jj = 0; jj < 4; ++jj){
        #pragma unroll
        for (int bb = 0; bb < 4; ++bb)
            gpart[((size_t)(d*GKS + ks)*BSZ + (b0+bb))*2048 + (j0+jj)] = acc[jj][bb];
    }
}

// ---------------- LSTM gates -> h, c ------------------------------------------------
__global__ void dnc_gates(const float* __restrict__ gpart,
                          const float* __restrict__ bih, const float* __restrict__ bhh,
                          float* __restrict__ cstate, float* __restrict__ hstate,
                          float* __restrict__ flat, float* __restrict__ lout, int l){
    int idx = blockIdx.x*256 + threadIdx.x;
    int u = idx & 511, b = (idx >> 9) & 31, d = idx >> 14;
    int cell = 2*l + d;
    float g[4];
    #pragma unroll
    for (int xg = 0; xg < 4; ++xg){
        int j = xg*512 + u;
        float s = bih[d*2048 + j] + bhh[d*2048 + j];
        #pragma unroll
        for (int ks = 0; ks < GKS; ++ks)
            s += gpart[((size_t)(d*GKS + ks)*BSZ + b)*2048 + j];
        g[xg] = s;
    }
    float ig = sigf(g[0]), fg = sigf(g[1]), og = sigf(g[3]);
    float gg = tanhf(g[2]);
    int ci = (cell*BSZ + b)*HD + u;
    float c2 = fg*cstate[ci] + ig*gg;
    cstate[ci] = c2;
    float h = og*tanhf(c2);
    hstate[ci] = h;
    flat[b*2048 + cell*HD + u] = h;
    if (lout) lout[b*1024 + d*HD + u] = h;
}

// ---------------- combined GEMV: flat@Wy (blocks 0-15) + flat@WE (blocks 16-19) ------
__global__ void dnc_gemv2(const float* __restrict__ fin, const float* __restrict__ Wy,
                          const float* __restrict__ WE,
                          float* __restrict__ vtp, float* __restrict__ ep){
    const int bx = blockIdx.x, ksi = blockIdx.y;
    const float* Wm; float* outp; int Mdim, mb;
    if (bx < 16){ Wm = Wy; outp = vtp; Mdim = VT; mb = bx; }
    else        { Wm = WE; outp = ep;  Mdim = ET; mb = bx - 16; }
    const int tid = threadIdx.x;
    const int lane = tid & 63, bg = tid >> 6;
    const int b0 = bg*8;
    const int m0 = mb*128 + lane, m1 = m0 + 64;
    const int k0 = ksi*128;
    __shared__ __align__(16) float tile[128*36];
    #pragma unroll
    for (int i = 0; i < 16; ++i){
        int idx = i*256 + tid; int kk = idx & 127, b = idx >> 7;
        tile[kk*36 + b] = fin[b*2048 + k0 + kk];
    }
    __syncthreads();
    bool v0 = m0 < Mdim, v1 = m1 < Mdim;
    float acc[16] = {0};
    for (int kk = 0; kk < 128; ++kk){
        float4 pq = *(const float4*)&tile[kk*36 + b0];
        float4 qq = *(const float4*)&tile[kk*36 + b0 + 4];
        const float* wr = Wm + (size_t)(k0+kk)*Mdim;
        float w0 = v0 ? wr[m0] : 0.f;
        float w1 = v1 ? wr[m1] : 0.f;
        acc[0]+=pq.x*w0; acc[1]+=pq.y*w0; acc[2]+=pq.z*w0; acc[3]+=pq.w*w0;
        acc[4]+=qq.x*w0; acc[5]+=qq.y*w0; acc[6]+=qq.z*w0; acc[7]+=qq.w*w0;
        acc[8]+=pq.x*w1; acc[9]+=pq.y*w1; acc[10]+=pq.z*w1; acc[11]+=pq.w*w1;
        acc[12]+=qq.x*w1; acc[13]+=qq.y*w1; acc[14]+=qq.z*w1; acc[15]+=qq.w*w1;
    }
    if (v0){
        #pragma unroll
        for (int bb = 0; bb < 8; ++bb)
            outp[((size_t)ksi*BSZ + b0+bb)*Mdim + m0] = acc[bb];
    }
    if (v1){
        #pragma unroll
        for (int bb = 0; bb < 8; ++bb)
            outp[((size_t)ksi*BSZ + b0+bb)*Mdim + m1] = acc[8+bb];
    }
}

// ---------------- presort: ln + usage + hybrid bitonic sort + shfl scan + alloc ------
// one block per b; no M traffic. j<64 bitonic stages via shfl (no barrier).
__global__ __launch_bounds__(1024) void dnc_presort(
    const float* __restrict__ ep, const float* __restrict__ lrw,
    const float* __restrict__ lww, float* __restrict__ ubuf,
    float* __restrict__ iv, float* __restrict__ allocw)
{
    const int b = blockIdx.x, tid = threadIdx.x;
    const int lane = tid & 63, wid = tid >> 6;
    __shared__ float red[32];
    __shared__ float ivS[464];
    __shared__ unsigned long long keysS[1024];
    __shared__ float wtot[16], wpref[16];

    // layernorm of WE partial sums
    float myv = 0.f;
    if (tid < ET){
        float v = 0.f;
        #pragma unroll
        for (int s = 0; s < VKS; ++s) v += ep[((size_t)s*BSZ + b)*ET + tid];
        myv = v;
    }
    float mean = bsum(myv, red, tid) * (1.f/ET);
    float dd = (tid < ET) ? (myv - mean) : 0.f;
    float var = bsum(dd*dd, red, tid) * (1.f/ET);
    float rinv = 1.f / sqrtf(var + 1e-5f);
    float ivv = (myv - mean)*rinv;
    if (tid < ET){ ivS[tid] = ivv; iv[b*ET + tid] = ivv; }
    __syncthreads();

    // usage
    const int n = tid;
    float4 lw4 = *(const float4*)&lrw[((size_t)b*1024 + n)*4];
    float f0 = sigf(ivS[453]), f1 = sigf(ivS[454]), f2 = sigf(ivS[455]), f3 = sigf(ivS[456]);
    float ret = (1.f-f0*lw4.x)*(1.f-f1*lw4.y)*(1.f-f2*lw4.z)*(1.f-f3*lw4.w);
    float uo = ubuf[b*1024+n], lwo = lww[b*1024+n];
    float un = (uo + lwo - uo*lwo)*ret;
    ubuf[b*1024+n] = un;

    // hybrid bitonic sort: LDS for j>=64, shfl for j<64 (u>=0 so uint order == float order)
    unsigned long long key = ((unsigned long long)__float_as_uint(un) << 32) | (unsigned)tid;
    for (int k = 2; k <= 1024; k <<= 1){
        int j = k >> 1;
        for (; j >= 64; j >>= 1){
            keysS[tid] = key; __syncthreads();
            unsigned long long other = keysS[tid ^ j];
            bool up = ((tid & k) == 0);
            bool takeMin = (((tid & j) == 0) == up);
            key = takeMin ? (key < other ? key : other) : (key > other ? key : other);
            __syncthreads();
        }
        for (; j >= 1; j >>= 1){
            unsigned long long other = __shfl_xor(key, j);
            bool up = ((tid & k) == 0);
            bool takeMin = (((tid & j) == 0) == up);
            key = takeMin ? (key < other ? key : other) : (key > other ? key : other);
        }
    }
    float su = __uint_as_float((unsigned)(key >> 32));
    int idxv = (int)(key & 0xffffffffu);

    // exclusive cumprod via wave shfl scan + 16 wave totals
    float p = su;
    #pragma unroll
    for (int o = 1; o < 64; o <<= 1){ float q = __shfl_up(p, o); if (lane >= o) p *= q; }
    if (lane == 63) wtot[wid] = p;
    __syncthreads();
    if (tid == 0){
        float r = 1.f;
        #pragma unroll
        for (int i = 0; i < 16; ++i){ wpref[i] = r; r *= wtot[i]; }
    }
    __syncthreads();
    float excl = __shfl_up(p, 1); if (lane == 0) excl = 1.f;
    float cpx = excl * wpref[wid];
    allocw[b*1024 + idxv] = (1.f - su)*cpx;
}

// ---------------- content write score (reads OLD M) ----------------------------------
__global__ void dnc_cw_score(const float* __restrict__ M, const float* __restrict__ iv,
                             float* __restrict__ scw){
    int b = blockIdx.x, tid = threadIdx.x;
    int n = blockIdx.y*256 + tid;
    __shared__ float key[64];
    if (tid < 64) key[tid] = iv[b*ET + 260 + tid];
    __syncthreads();
    float ksq = 0.f;
    #pragma unroll
    for (int w = 0; w < 64; ++w) ksq += key[w]*key[w];
    float kden = sqrtf(ksq) + 1e-8f;
    float wb = 1.f - logsigf(iv[b*ET + 324]);
    const float* Mrow = M + ((size_t)b*1024 + n)*64;
    float dot = 0.f, msq = 0.f;
    #pragma unroll
    for (int w = 0; w < 64; w += 4){
        float4 mv = *(const float4*)(Mrow + w);
        dot += mv.x*key[w] + mv.y*key[w+1] + mv.z*key[w+2] + mv.w*key[w+3];
        msq += mv.x*mv.x + mv.y*mv.y + mv.z*mv.z + mv.w*mv.w;
    }
    scw[b*1024 + n] = wb * dot / ((sqrtf(msq) + 1e-8f) * kden);
}

// ---------------- content write softmax + ww ----------------------------------------
__global__ void dnc_cw_ww(const float* __restrict__ scw, const float* __restrict__ allocw,
                          const float* __restrict__ iv, float* __restrict__ lww){
    int b = blockIdx.x, tid = threadIdx.x;
    __shared__ float red[4];
    float v[4];
    #pragma unroll
    for (int i = 0; i < 4; ++i) v[i] = scw[b*1024 + i*256 + tid];
    float mx = fmaxf(fmaxf(v[0],v[1]), fmaxf(v[2],v[3]));
    mx = bmax256(mx, red, tid);
    float ls = 0.f;
    #pragma unroll
    for (int i = 0; i < 4; ++i) ls += expf(v[i]-mx);
    float tot = bsum256(ls, red, tid);
    float wg = sigf(iv[b*ET + 458]);
    float ag = sigf(iv[b*ET + 457]);
    #pragma unroll
    for (int i = 0; i < 4; ++i){
        int n = i*256 + tid;
        float cw = expf(v[i]-mx) / tot;
        lww[b*1024 + n] = wg * (ag*allocw[b*1024 + n] + (1.f-ag)*cw);
    }
}

// ---------------- fused: memory update + row norm + read scores ----------------------
__global__ void dnc_memup_rd(float* __restrict__ M, const float* __restrict__ lww,
                             const float* __restrict__ iv, float* __restrict__ scr){
    const int b = blockIdx.x, tid = threadIdx.x;
    const int n = blockIdx.y*256 + tid;
    __shared__ float eraseS[64], wvecS[64], rknS[256], nrmS[4], rbS[4];
    if (tid < 64){ eraseS[tid] = sigf(iv[b*ET + 325 + tid]); wvecS[tid] = iv[b*ET + 389 + tid]; }
    if (tid >= 64 && tid < 320) rknS[tid-64] = iv[b*ET + (tid-64)];
    __syncthreads();
    if (tid < 4){
        float s = 0.f;
        #pragma unroll
        for (int w = 0; w < 64; ++w){ float v = rknS[w*4 + tid]; s += v*v; }
        nrmS[tid] = sqrtf(s) + 1e-8f;
        rbS[tid] = 1.f - logsigf(iv[b*ET + 256 + tid]);
    }
    __syncthreads();
    if (tid < 256) rknS[tid] = rknS[tid] / nrmS[tid & 3];
    __syncthreads();

    float wwv = lww[b*1024 + n];
    float* Mrow = M + ((size_t)b*1024 + n)*64;
    float dr0=0.f, dr1=0.f, dr2=0.f, dr3=0.f, msq2=0.f;
    #pragma unroll
    for (int w = 0; w < 64; w += 4){
        float4 mv = *(const float4*)(Mrow + w);
        mv.x = mv.x*(1.f - wwv*eraseS[w+0]) + wwv*wvecS[w+0];
        mv.y = mv.y*(1.f - wwv*eraseS[w+1]) + wwv*wvecS[w+1];
        mv.z = mv.z*(1.f - wwv*eraseS[w+2]) + wwv*wvecS[w+2];
        mv.w = mv.w*(1.f - wwv*eraseS[w+3]) + wwv*wvecS[w+3];
        *(float4*)(Mrow + w) = mv;
        msq2 += mv.x*mv.x + mv.y*mv.y + mv.z*mv.z + mv.w*mv.w;
        dr0 += mv.x*rknS[(w+0)*4+0] + mv.y*rknS[(w+1)*4+0] + mv.z*rknS[(w+2)*4+0] + mv.w*rknS[(w+3)*4+0];
        dr1 += mv.x*rknS[(w+0)*4+1] + mv.y*rknS[(w+1)*4+1] + mv.z*rknS[(w+2)*4+1] + mv.w*rknS[(w+3)*4+1];
        dr2 += mv.x*rknS[(w+0)*4+2] + mv.y*rknS[(w+1)*4+2] + mv.z*rknS[(w+2)*4+2] + mv.w*rknS[(w+3)*4+2];
        dr3 += mv.x*rknS[(w+0)*4+3] + mv.y*rknS[(w+1)*4+3] + mv.z*rknS[(w+2)*4+3] + mv.w*rknS[(w+3)*4+3];
    }
    float den = sqrtf(msq2) + 1e-8f;
    scr[((size_t)(b*4 + 0))*1024 + n] = rbS[0]*dr0/den;
    scr[((size_t)(b*4 + 1))*1024 + n] = rbS[1]*dr1/den;
    scr[((size_t)(b*4 + 2))*1024 + n] = rbS[2]*dr2/den;
    scr[((size_t)(b*4 + 3))*1024 + n] = rbS[3]*dr3/den;
}

// ---------------- read softmax -> lrw ------------------------------------------------
__global__ void dnc_rd_sm(const float* __restrict__ scr, float* __restrict__ lrw){
    int br = blockIdx.x, tid = threadIdx.x;
    int b = br >> 2, r = br & 3;
    __shared__ float red[4];
    float v[4];
    #pragma unroll
    for (int i = 0; i < 4; ++i) v[i] = scr[(size_t)br*1024 + i*256 + tid];
    float mx = fmaxf(fmaxf(v[0],v[1]), fmaxf(v[2],v[3]));
    mx = bmax256(mx, red, tid);
    float ls = 0.f;
    #pragma unroll
    for (int i = 0; i < 4; ++i) ls += expf(v[i]-mx);
    float tot = bsum256(ls, red, tid);
    #pragma unroll
    for (int i = 0; i < 4; ++i){
        int n = i*256 + tid;
        lrw[((size_t)b*1024 + n)*4 + r] = expf(v[i]-mx)/tot;
    }
}

// ---------------- read vectors (n-split partials) -----------------------------------
__global__ void dnc_rv(const float* __restrict__ M, const float* __restrict__ lrw,
                       float* __restrict__ rvp){
    int b = blockIdx.x, ns = blockIdx.y;
    int r = threadIdx.x >> 6, w = threadIdx.x & 63;
    float acc = 0.f;
    for (int i = 0; i < 256; ++i){
        int n = ns*256 + i;
        acc += M[((size_t)b*1024 + n)*64 + w] * lrw[((size_t)b*1024 + n)*4 + r];
    }
    rvp[((size_t)(ns*BSZ + b))*256 + r*64 + w] = acc;
}

// ---------------- final: sum rvp -> lrv(tile+global), yt = rv@Wr + vtp; out max ------
__global__ void dnc_yfin(const float* __restrict__ rvp, const float* __restrict__ Wr,
                         const float* __restrict__ vtp, float* __restrict__ lrv,
                         float* __restrict__ out, int t){
    const int tid = threadIdx.x;
    const int mg = tid & 31, bg = tid >> 5;
    const int m0 = blockIdx.x*128 + mg*4;
    const int b0 = bg*4;
    __shared__ __align__(16) float lt[256*36];   // lrv^T [k][b]; k = w*4+r
    #pragma unroll
    for (int i = 0; i < 32; ++i){
        int idx = i*256 + tid; int k = idx & 255, b = idx >> 8;
        int w = k >> 2, r = k & 3;
        int ksrc = r*64 + w;
        float s = 0.f;
        #pragma unroll
        for (int c = 0; c < 4; ++c) s += rvp[((size_t)(c*BSZ + b))*256 + ksrc];
        lt[k*36 + b] = s;
        if (blockIdx.x == 0) lrv[b*256 + k] = s;
    }
    __syncthreads();
    float acc[4][4] = {{0}};
    for (int kk = 0; kk < 256; ++kk){
        float4 av = *(const float4*)&lt[kk*36 + b0];
        float4 wv = *(const float4*)&Wr[(size_t)kk*VT + m0];
        acc[0][0]+=av.x*wv.x; acc[0][1]+=av.x*wv.y; acc[0][2]+=av.x*wv.z; acc[0][3]+=av.x*wv.w;
        acc[1][0]+=av.y*wv.x; acc[1][1]+=av.y*wv.y; acc[1][2]+=av.y*wv.z; acc[1][3]+=av.y*wv.w;
        acc[2][0]+=av.z*wv.x; acc[2][1]+=av.z*wv.y; acc[2][2]+=av.z*wv.z; acc[2][3]+=av.z*wv.w;
        acc[3][0]+=av.w*wv.x; acc[3][1]+=av.w*wv.y; acc[3][2]+=av.w*wv.z; acc[3][3]+=av.w*wv.w;
    }
    #pragma unroll
    for (int bi = 0; bi < 4; ++bi){
        int b = b0 + bi;
        float4 s = make_float4(acc[bi][0], acc[bi][1], acc[bi][2], acc[bi][3]);
        #pragma unroll
        for (int sp = 0; sp < VKS; ++sp){
            float4 vp = *(const float4*)&vtp[((size_t)sp*BSZ + b)*VT + m0];
            s.x += vp.x; s.y += vp.y; s.z += vp.z; s.w += vp.w;
        }
        float4* op = (float4*)&out[(size_t)b*VT + m0];
        if (t == 0){ *op = s; }
        else {
            float4 cur = *op;
            cur.x = fmaxf(cur.x, s.x); cur.y = fmaxf(cur.y, s.y);
            cur.z = fmaxf(cur.z, s.z); cur.w = fmaxf(cur.w, s.w);
            *op = cur;
        }
    }
}

extern "C" void kernel_launch(void* const* d_in, const int* in_sizes, int n_in,
                              void* d_out, int out_size, void* d_ws, size_t ws_size,
                              hipStream_t stream){
    const float* x      = (const float*)d_in[0];
    const float* mem0   = (const float*)d_in[1];
    const float* Wy     = (const float*)d_in[2];
    const float* WE     = (const float*)d_in[3];
    const float* Wr     = (const float*)d_in[4];
    const float* Wih0   = (const float*)d_in[5];
    const float* Whh0   = (const float*)d_in[6];
    const float* bih0   = (const float*)d_in[7];
    const float* bhh0   = (const float*)d_in[8];
    const float* Wih1   = (const float*)d_in[9];
    const float* Whh1   = (const float*)d_in[10];
    const float* bih1   = (const float*)d_in[11];
    const float* bhh1   = (const float*)d_in[12];
    float* out = (float*)d_out;

    float* p = (float*)d_ws;
    float* M      = p; p += (size_t)32*1024*64;
    float* hstate = p; p += 4*32*512;     // zero block start
    float* cstate = p; p += 4*32*512;
    float* ubuf   = p; p += 32*1024;
    float* lww    = p; p += 32*1024;
    float* lrw    = p; p += 32*1024*4;
    float* lrv    = p; p += 32*256;       // zero block end
    float* bnx    = p; p += (size_t)TT*32*128;
    float* lin1   = p; p += 32*1024;
    float* gpart  = p; p += (size_t)2*GKS*32*2048;
    float* flat   = p; p += 32*2048;
    float* vtp    = p; p += (size_t)VKS*32*2048;
    float* ep     = p; p += (size_t)VKS*32*ET;
    float* iv     = p; p += 32*ET;
    float* allocw = p; p += 32*1024;
    float* scw    = p; p += 32*1024;
    float* scr    = p; p += 32*4*1024;
    float* rvp    = p; p += 4*32*256;

    (void)hipMemcpyAsync(M, mem0, (size_t)32*1024*64*sizeof(float), hipMemcpyDeviceToDevice, stream);
    size_t zfloats = (size_t)(4*32*512)*2 + 32*1024*2 + 32*1024*4 + 32*256;
    (void)hipMemsetAsync(hstate, 0, zfloats*sizeof(float), stream);

    dnc_bnx<<<TT, 128, 0, stream>>>(x, bnx);

    for (int t = 0; t < TT; ++t){
        dnc_lstm_gemm<<<dim3(16,2,GKS), 256, 0, stream>>>(bnx + (size_t)t*32*128, 128,
                                                          lrv, 256, hstate, Wih0, Whh0, gpart);
        dnc_gates<<<128, 256, 0, stream>>>(gpart, bih0, bhh0, cstate, hstate, flat, lin1, 0);
        dnc_lstm_gemm<<<dim3(16,2,GKS), 256, 0, stream>>>(lin1, 1024, nullptr, 0,
                                                          hstate + 2*32*512, Wih1, Whh1, gpart);
        dnc_gates<<<128, 256, 0, stream>>>(gpart, bih1, bhh1, cstate, hstate, flat, nullptr, 1);
        dnc_gemv2<<<dim3(20,VKS), 256, 0, stream>>>(flat, Wy, WE, vtp, ep);
        dnc_presort<<<32, 1024, 0, stream>>>(ep, lrw, lww, ubuf, iv, allocw);
        dnc_cw_score<<<dim3(32,4), 256, 0, stream>>>(M, iv, scw);
        dnc_cw_ww<<<32, 256, 0, stream>>>(scw, allocw, iv, lww);
        dnc_memup_rd<<<dim3(32,4), 256, 0, stream>>>(M, lww, iv, scr);
        dnc_rd_sm<<<128, 256, 0, stream>>>(scr, lrw);
        dnc_rv<<<dim3(32,4), 256, 0, stream>>>(M, lrw, rvp);
        dnc_yfin<<<16, 256, 0, stream>>>(rvp, Wr, vtp, lrv, out, t);
    }
}